// Round 1
// 2727.690 us; speedup vs baseline: 1.2640x; 1.2640x over previous
//
#include <hip/hip_runtime.h>
#include <math.h>

#define BATCH 32
#define SEQT 384
#define DIM 768
#define D3 2304
#define NROWS (BATCH*SEQT)      // 12288
#define VTHRESH 0.95f

typedef float  f32x4 __attribute__((ext_vector_type(4)));

// ---------------- workspace layout (bytes) ----------------
#define OFF_XP   ((size_t)0)
#define SZ_XP    ((size_t)NROWS * D3 * 4)            // 113,246,208
#define OFF_ST   (OFF_XP + SZ_XP)
#define SZ_ST    ((size_t)NROWS * DIM * 4)           // 37,748,736
#define OFF_PR   (OFF_ST + SZ_ST)
#define SZ_PR    ((size_t)NROWS * 4)
#define OFF_WT   (OFF_PR + SZ_PR)
#define OFF_SS   (OFF_WT + SZ_PR)
#define OFF_SE   (OFF_SS + SZ_PR)
#define OFF_NS   (OFF_SE + SZ_PR)
#define OFF_HB   (OFF_NS + 256)
// hbuf: 2 parity x 4 bg x 768 cols x 3 chunks x 16B = 294,912 B
#define NBG 4               // batch groups (8 batches each)
#define BPG 8               // batches per group
#define CPB 12              // h-columns per WG (64 WGs per bg)
#define HCH 3               // 16B chunks per column (3 vals + tag each)
#define BGBYTES ((size_t)(DIM * HCH * 16))   // 36,864
#define SZ_HB   ((size_t)2 * NBG * BGBYTES)  // 294,912

#define DOT4(a,b) ((a).x*(b).x + (a).y*(b).y + (a).z*(b).z + (a).w*(b).w)

// =========================================================
// K1: xp[m][n] = sum_k emb[sent[m]][k] * w_ih[n][k] + b_ih[n]
// =========================================================
__global__ __launch_bounds__(256, 2) void k_xp(
    const int* __restrict__ sent, const float* __restrict__ emb,
    const float* __restrict__ w_ih, const float* __restrict__ b_ih,
    float* __restrict__ xp)
{
    __shared__ float As[16][132];
    __shared__ float Bs[16][132];
    const int tid = threadIdx.x;
    const int mt = blockIdx.x, nt = blockIdx.y;
    const int tx = tid & 15, ty = tid >> 4;
    const int lm = tid >> 2;          // 0..63
    const int lk = (tid & 3) << 2;    // 0,4,8,12

    const long arow0 = (long)sent[mt*128 + lm] * DIM;
    const long arow1 = (long)sent[mt*128 + lm + 64] * DIM;
    const float* b0p = w_ih + (size_t)(nt*128 + lm) * DIM;
    const float* b1p = w_ih + (size_t)(nt*128 + lm + 64) * DIM;

    float acc[8][8];
    #pragma unroll
    for (int i = 0; i < 8; ++i)
        #pragma unroll
        for (int j = 0; j < 8; ++j) acc[i][j] = 0.f;

    for (int k0 = 0; k0 < DIM; k0 += 16) {
        float4 a0 = *(const float4*)(emb + arow0 + k0 + lk);
        float4 a1 = *(const float4*)(emb + arow1 + k0 + lk);
        float4 b0 = *(const float4*)(b0p + k0 + lk);
        float4 b1 = *(const float4*)(b1p + k0 + lk);
        __syncthreads();
        As[lk+0][lm] = a0.x; As[lk+1][lm] = a0.y; As[lk+2][lm] = a0.z; As[lk+3][lm] = a0.w;
        As[lk+0][lm+64] = a1.x; As[lk+1][lm+64] = a1.y; As[lk+2][lm+64] = a1.z; As[lk+3][lm+64] = a1.w;
        Bs[lk+0][lm] = b0.x; Bs[lk+1][lm] = b0.y; Bs[lk+2][lm] = b0.z; Bs[lk+3][lm] = b0.w;
        Bs[lk+0][lm+64] = b1.x; Bs[lk+1][lm+64] = b1.y; Bs[lk+2][lm+64] = b1.z; Bs[lk+3][lm+64] = b1.w;
        __syncthreads();
        #pragma unroll
        for (int k = 0; k < 16; ++k) {
            float4 av0 = *(const float4*)&As[k][ty*8];
            float4 av1 = *(const float4*)&As[k][ty*8+4];
            float4 bv0 = *(const float4*)&Bs[k][tx*8];
            float4 bv1 = *(const float4*)&Bs[k][tx*8+4];
            float a[8] = {av0.x,av0.y,av0.z,av0.w,av1.x,av1.y,av1.z,av1.w};
            float b[8] = {bv0.x,bv0.y,bv0.z,bv0.w,bv1.x,bv1.y,bv1.z,bv1.w};
            #pragma unroll
            for (int i = 0; i < 8; ++i)
                #pragma unroll
                for (int j = 0; j < 8; ++j)
                    acc[i][j] += a[i]*b[j];
        }
    }

    const int m0 = mt*128 + ty*8;
    const int n0 = nt*128 + tx*8;
    float4 bi0 = *(const float4*)(b_ih + n0);
    float4 bi1 = *(const float4*)(b_ih + n0 + 4);
    #pragma unroll
    for (int i = 0; i < 8; ++i) {
        float4 v0, v1;
        v0.x = acc[i][0] + bi0.x; v0.y = acc[i][1] + bi0.y;
        v0.z = acc[i][2] + bi0.z; v0.w = acc[i][3] + bi0.w;
        v1.x = acc[i][4] + bi1.x; v1.y = acc[i][5] + bi1.y;
        v1.z = acc[i][6] + bi1.z; v1.w = acc[i][7] + bi1.w;
        *(float4*)(xp + (size_t)(m0+i)*D3 + n0)     = v0;
        *(float4*)(xp + (size_t)(m0+i)*D3 + n0 + 4) = v1;
    }
}

// =========================================================
// K2: persistent GRU recurrence, v5 — restructured exchange.
//   vs v4b:
//   - 4 batch-groups x 64 col-WGs (was 2x128): per-WG polled data
//     36KB (was 64KB), fan-in 64 producers (was 128), grid spin
//     traffic 9MB/sweep (was 16MB).
//   - chunk = [h(b0),h(b1),h(b2),tag] per COLUMN ([col][batch] global
//     layout): the 3 values come from ONE wave, so each wave packs via
//     __shfl and publishes immediately after its reduce. out_lds and
//     the second __syncthreads are gone; publish no longer waits for
//     the slowest wave in the WG.
//   - tags out of k-space: Phase B is contiguous-k (576 real FMAs, was
//     768 incl. tag-zero slots); weights are direct float4 loads.
//   - h_lds double-buffered -> ONE __syncthreads per step; poll spread
//     over all 384 threads (6 chunks each).
//   - sched_barrier(0) after inline vmcnt(0) (rule #18: keeps the tag
//     compare from hoisting above the wait).
// =========================================================
#define HPITCH 772   // 768 + 4: de-bank the transpose fill writes

__global__ __launch_bounds__(384, 1) void k_gru(
    const float* __restrict__ w_hh, const float* __restrict__ b_hh,
    const float* __restrict__ xp, float* __restrict__ states,
    char* __restrict__ hbuf)
{
    __shared__ float h_lds[2][BPG][HPITCH];   // 49,408 B

    const int tid = threadIdx.x;
    const int jb  = blockIdx.x & 63;
    const int bg  = blockIdx.x >> 6;
    const int j    = tid >> 6;         // wave 0..5
    const int lane = tid & 63;
    const int c    = lane & 31;
    const int bh   = lane >> 5;        // which of the wave's 2 columns
    const int col  = jb*CPB + j*2 + bh;
    const int bloc = (c >> 2) & 7;
    const int batch = bg*BPG + bloc;

    // weights: gate g, contiguous k-slice {c*4 + kk*128}
    float4 w4[3][6];
    #pragma unroll
    for (int g3 = 0; g3 < 3; ++g3) {
        const float* wr = w_hh + (size_t)(g3*DIM + col)*DIM + c*4;
        #pragma unroll
        for (int kk = 0; kk < 6; ++kk)
            w4[g3][kk] = *(const float4*)(wr + kk*128);
    }
    const float bhr = b_hh[col];
    const float bhz = b_hh[DIM + col];
    const float bhn = b_hh[2*DIM + col];

    // poll assignment: chunk q = i*384 + tid; col_q = q/3, s_q = q%3
    int goff[6], ldsoff[6], lastm = 0;
    #pragma unroll
    for (int i = 0; i < 6; ++i) {
        int q = i*384 + tid;
        int cq = q/3, sq = q - 3*cq;
        goff[i]   = q << 4;
        ldsoff[i] = (3*sq)*HPITCH + cq;     // h_lds[3s+{0,1,2}][col_q]
        if (sq == 2) lastm |= (1<<i);       // s=2 carries only 2 values
    }

    char* pb_par[2];
    pb_par[0] = hbuf + (size_t)(0*NBG + bg)*BGBYTES;
    pb_par[1] = hbuf + (size_t)(1*NBG + bg)*BGBYTES;

    const float* xq = xp + ((size_t)batch*SEQT)*D3 + col;

    float hold = 0.f;

    for (int t = 0; t < SEQT; ++t) {
        // xp prefetch — independent of the exchange, issue first
        float xr = xq[0], xz = xq[DIM], xn = xq[2*DIM];
        xq += D3;

        if (t > 0) {
            // ---- poll step t-1 chunks (all 384 threads, 6 each)
            const char* pb = pb_par[(t-1)&1];
            f32x4 ch[6];
            int need = 63;
            while (need) {
                #pragma unroll
                for (int k = 0; k < 6; ++k)
                    if (need & (1<<k)) {
                        const f32x4* ap = (const f32x4*)(pb + goff[k]);
                        asm volatile("global_load_dwordx4 %0, %1, off sc0 sc1"
                                     : "=v"(ch[k]) : "v"(ap));
                    }
                asm volatile("s_waitcnt vmcnt(0)" ::: "memory");
                __builtin_amdgcn_sched_barrier(0);
                #pragma unroll
                for (int k = 0; k < 6; ++k)
                    if ((need & (1<<k)) && __float_as_int(ch[k].w) == t)
                        need &= ~(1<<k);
                if (need) __builtin_amdgcn_s_sleep(1);
            }
            // ---- transposed fill: h_lds[buf][batch][element]
            float* hb0 = &h_lds[t & 1][0][0];
            #pragma unroll
            for (int k = 0; k < 6; ++k) {
                hb0[ldsoff[k]]            = ch[k].x;
                hb0[ldsoff[k] + HPITCH]   = ch[k].y;
                if (!((lastm >> k) & 1))
                    hb0[ldsoff[k] + 2*HPITCH] = ch[k].z;
            }
        }
        __syncthreads();

        float ar = 0.f, az = 0.f, an = 0.f;
        if (t > 0) {
            // ---- Phase B: partial dots, 8 batches x 3 gates, slice c
            float v[24];
            #pragma unroll
            for (int i = 0; i < 24; ++i) v[i] = 0.f;
            const float* hbase = &h_lds[t & 1][0][c*4];
            #pragma unroll
            for (int bb = 0; bb < 8; ++bb) {
                const float* hr = hbase + bb*HPITCH;
                #pragma unroll
                for (int kk = 0; kk < 6; ++kk) {
                    float4 h4 = *(const float4*)(hr + kk*128);
                    v[bb*3+0] += DOT4(h4, w4[0][kk]);
                    v[bb*3+1] += DOT4(h4, w4[1][kk]);
                    v[bb*3+2] += DOT4(h4, w4[2][kk]);
                }
            }
            // ---- reduce-scatter over the 32 c-lanes (bits 4,3,2 -> batch)
            #pragma unroll
            for (int i = 0; i < 12; ++i) {
                float send = (c & 16) ? v[i] : v[i+12];
                float keep = (c & 16) ? v[i+12] : v[i];
                v[i] = keep + __shfl_xor(send, 16);
            }
            #pragma unroll
            for (int i = 0; i < 6; ++i) {
                float send = (c & 8) ? v[i] : v[i+6];
                float keep = (c & 8) ? v[i+6] : v[i];
                v[i] = keep + __shfl_xor(send, 8);
            }
            #pragma unroll
            for (int i = 0; i < 3; ++i) {
                float send = (c & 4) ? v[i] : v[i+3];
                float keep = (c & 4) ? v[i+3] : v[i];
                v[i] = keep + __shfl_xor(send, 4);
            }
            #pragma unroll
            for (int i = 0; i < 3; ++i) v[i] += __shfl_xor(v[i], 2);
            #pragma unroll
            for (int i = 0; i < 3; ++i) v[i] += __shfl_xor(v[i], 1);
            ar = v[0]; az = v[1]; an = v[2];
        }

        float rg = 1.f / (1.f + expf(-(xr + ar + bhr)));
        float zg = 1.f / (1.f + expf(-(xz + az + bhz)));
        float ng = tanhf(xn + rg * (an + bhn));
        hold = (1.f - zg) * ng + zg * hold;

        // ---- per-wave immediate publish: 3 tagged chunks per column
        {
            int s_pub = c >> 2;            // meaningful for c in {0,4,8}
            int bb0 = 3*s_pub;
            int basel = lane & 32;
            float p0 = __shfl(hold, basel + ((4*(bb0+0)) & 31));
            float p1 = __shfl(hold, basel + ((4*(bb0+1)) & 31));
            float p2 = __shfl(hold, basel + ((4*(bb0+2)) & 31));
            if (((c & 3) == 0) && (c < 12)) {
                f32x4 val;
                val.x = p0; val.y = p1; val.z = p2;
                val.w = __int_as_float(t + 1);
                f32x4* ap = (f32x4*)(pb_par[t & 1]
                                     + (size_t)(col*HCH + s_pub)*16);
                asm volatile("global_store_dwordx4 %0, %1, off sc0 sc1"
                             :: "v"(ap), "v"(val) : "memory");
            }
        }
        if ((c & 3) == 0)
            states[(size_t)(batch*SEQT + t)*DIM + col] = hold;  // plain cached
    }
}

// =========================================================
// K3: probs[r] = sigmoid(dot(states[r], w_act) + b_act)
// =========================================================
__global__ __launch_bounds__(256, 4) void k_probs(
    const float* __restrict__ states, const float* __restrict__ w_act,
    const float* __restrict__ b_act, float* __restrict__ probs,
    float* __restrict__ out_probs)
{
    int row  = blockIdx.x*4 + (threadIdx.x >> 6);
    int lane = threadIdx.x & 63;
    const float* sr = states + (size_t)row * DIM;
    float s = 0.f;
    #pragma unroll
    for (int i = 0; i < 3; ++i) {
        float4 v = *(const float4*)(sr + i*256 + lane*4);
        float4 w = *(const float4*)(w_act + i*256 + lane*4);
        s += v.x*w.x + v.y*w.y + v.z*w.z + v.w*w.w;
    }
    #pragma unroll
    for (int off = 32; off > 0; off >>= 1) s += __shfl_xor(s, off);
    if (lane == 0) {
        float pv = 1.f / (1.f + expf(-(s + b_act[0])));
        probs[row]     = pv;
        out_probs[row] = pv;
    }
}

// =========================================================
// K4: per-batch halting scan -> weights, segment bounds, n_segs
// =========================================================
__global__ void k_scan(const float* __restrict__ probs, float* __restrict__ weights,
                       int* __restrict__ seg_start, int* __restrict__ seg_end,
                       int* __restrict__ n_segs)
{
    int b = threadIdx.x;
    if (b >= BATCH) return;
    float acc = 0.f;
    int s = 0, start = 0;
    for (int t0 = 0; t0 < SEQT; t0 += 4) {
        float4 p4 = *(const float4*)(probs + b*SEQT + t0);
        float pv[4] = {p4.x, p4.y, p4.z, p4.w};
        #pragma unroll
        for (int k = 0; k < 4; ++k) {
            int t = t0 + k;
            float pp = pv[k];
            acc += pp;
            float w = pp;
            if (acc > VTHRESH) {
                w = pp - (acc - 1.0f);
                seg_start[b*SEQT + s] = start;
                seg_end[b*SEQT + s]   = t;
                s++; start = t + 1; acc = 0.f;
            }
            weights[b*SEQT + t] = w;
        }
    }
    n_segs[b] = s;
}

// =========================================================
// K5: embs row (b,s) = sum_{t in segment s} weights[b,t]*states[b,t,:]
// =========================================================
__global__ __launch_bounds__(256, 4) void k_embs(
    const float* __restrict__ states, const float* __restrict__ weights,
    const int* __restrict__ seg_start, const int* __restrict__ seg_end,
    const int* __restrict__ n_segs, float* __restrict__ out)
{
    int r = blockIdx.x;
    int b = r / SEQT;
    int s = r - b*SEQT;
    int tid = threadIdx.x;
    float a0 = 0.f, a1 = 0.f, a2 = 0.f;
    if (s < n_segs[b]) {
        int st = seg_start[r], en = seg_end[r];
        for (int t = st; t <= en; ++t) {
            float w = weights[b*SEQT + t];
            const float* sp = states + (size_t)(b*SEQT + t) * DIM;
            a0 += w * sp[tid];
            a1 += w * sp[tid + 256];
            a2 += w * sp[tid + 512];
        }
    }
    float* o = out + (size_t)r * DIM;
    o[tid]       = a0;
    o[tid + 256] = a1;
    o[tid + 512] = a2;
}

__global__ void k_init(float* hb) {
    hb[blockIdx.x * 256 + threadIdx.x] = 0.f;   // 73728 floats = 288KB
}

extern "C" void kernel_launch(void* const* d_in, const int* in_sizes, int n_in,
                              void* d_out, int out_size, void* d_ws, size_t ws_size,
                              hipStream_t stream)
{
    const int*   sent  = (const int*)d_in[0];
    const float* emb   = (const float*)d_in[1];
    const float* w_ih  = (const float*)d_in[2];
    const float* w_hh  = (const float*)d_in[3];
    const float* b_ih  = (const float*)d_in[4];
    const float* b_hh  = (const float*)d_in[5];
    const float* w_act = (const float*)d_in[6];
    const float* b_act = (const float*)d_in[7];
    float* out = (float*)d_out;

    char* ws = (char*)d_ws;
    float* xp      = (float*)(ws + OFF_XP);
    float* states  = (float*)(ws + OFF_ST);
    float* probs   = (float*)(ws + OFF_PR);
    float* weights = (float*)(ws + OFF_WT);
    int*   sstart  = (int*)(ws + OFF_SS);
    int*   send    = (int*)(ws + OFF_SE);
    int*   nsegs   = (int*)(ws + OFF_NS);
    char*  hbuf    = (char*)(ws + OFF_HB);

    k_init<<<288, 256, 0, stream>>>((float*)hbuf);
    k_xp<<<dim3(96, 18), 256, 0, stream>>>(sent, emb, w_ih, b_ih, xp);
    k_gru<<<256, 384, 0, stream>>>(w_hh, b_hh, xp, states, hbuf);
    k_probs<<<NROWS/4, 256, 0, stream>>>(states, w_act, b_act, probs,
                                         out + (size_t)NROWS * DIM);
    k_scan<<<1, 64, 0, stream>>>(probs, weights, sstart, send, nsegs);
    k_embs<<<NROWS, 256, 0, stream>>>(states, weights, sstart, send, nsegs, out);
}